// Round 2
// baseline (164.186 us; speedup 1.0000x reference)
//
#include <hip/hip_runtime.h>
#include <math.h>

// Problem constants (from reference)
#define NB      2048        // batch
#define DIM     256         // input dim
#define SC6     192         // S*6 = 32 splines * 6 params
#define CV      128         // canvas size
#define NT      50          // samples along curve
#define CWORDS  (CV * CV / 4)   // 4096 u8-packed words per canvas
// W_STAMP = -0.07, BG = 0.3, SCALE = 1e-4

// log_prob per batch = 192*( -ln(1e-4) - 0.5*ln(2*pi) )  (raw == mu exactly)
// entropy  per batch = 192*( 0.5 + 0.5*ln(2*pi) + ln(1e-4) )
#define LPV  (1591.9491530441301f)
#define ENV  (-1495.9491530441301f)

// Output layout (flat, return order): sketch | log_prob | entropy | sample
#define SKETCH_N   ((size_t)NB * CV * CV)     // 33,554,432
#define LP_OFF     (SKETCH_N)
#define ENT_OFF    (LP_OFF + NB)
#define SAMPLE_OFF (ENT_OFF + NB)

typedef float vfloat4 __attribute__((ext_vector_type(4)));

// Workgroup barrier waiting ONLY on LDS ops (lgkmcnt), not global stores.
__device__ __forceinline__ void barrier_lds_only() {
    asm volatile("s_waitcnt lgkmcnt(0)\n\ts_barrier" ::: "memory");
}

// ---------------------------------------------------------------------------
// Kernel A — GEMM + sigmoid only. 512 blocks x 192 threads, 4 batches/thread.
// Shaped for the GEMM: 8 independent f64 FMA chains (ILP), W loaded once per
// 4 batches (512 x 196 KB = 100 MB from L2), x loads wave-uniform (s_load).
// Per-batch accumulation order is BIT-IDENTICAL to the previous passing
// kernel: even-d chain a?0, odd-d chain a?1, then (a?0 + a?1) + bias.
// Writes sample (f32) / log_prob / entropy. Paint kernel re-reads sample.
// ---------------------------------------------------------------------------
__global__ __launch_bounds__(192) void gemm_kernel(
    const float* __restrict__ x, const float* __restrict__ W,
    const float* __restrict__ bias, float* __restrict__ out)
{
    const int b0 = blockIdx.x * 4;
    const int j  = threadIdx.x;                   // 0..191
    const float* xb = x + (size_t)b0 * DIM;       // wave-uniform -> s_load

    double a00 = 0.0, a01 = 0.0, a10 = 0.0, a11 = 0.0;
    double a20 = 0.0, a21 = 0.0, a30 = 0.0, a31 = 0.0;
    #pragma unroll 4
    for (int d = 0; d < DIM; d += 2) {
        double w0 = (double)W[d * SC6 + j];
        double w1 = (double)W[(d + 1) * SC6 + j];
        a00 = fma((double)xb[d],               w0, a00);
        a01 = fma((double)xb[d + 1],           w1, a01);
        a10 = fma((double)xb[DIM + d],         w0, a10);
        a11 = fma((double)xb[DIM + d + 1],     w1, a11);
        a20 = fma((double)xb[2 * DIM + d],     w0, a20);
        a21 = fma((double)xb[2 * DIM + d + 1], w1, a21);
        a30 = fma((double)xb[3 * DIM + d],     w0, a30);
        a31 = fma((double)xb[3 * DIM + d + 1], w1, a31);
    }
    double bj = (double)bias[j];
    double s0 = 1.0 / (1.0 + exp(-((a00 + a01) + bj)));
    double s1 = 1.0 / (1.0 + exp(-((a10 + a11) + bj)));
    double s2 = 1.0 / (1.0 + exp(-((a20 + a21) + bj)));
    double s3 = 1.0 / (1.0 + exp(-((a30 + a31) + bj)));
    out[SAMPLE_OFF + (size_t)b0 * SC6 + j]       = (float)s0;
    out[SAMPLE_OFF + (size_t)(b0 + 1) * SC6 + j] = (float)s1;
    out[SAMPLE_OFF + (size_t)(b0 + 2) * SC6 + j] = (float)s2;
    out[SAMPLE_OFF + (size_t)(b0 + 3) * SC6 + j] = (float)s3;
    if (j < 4) {
        out[LP_OFF  + b0 + j] = LPV;
        out[ENT_OFF + b0 + j] = ENV;
    }
}

// ---------------------------------------------------------------------------
// Kernel B — paint + epilogue only. 2048 blocks x 256 threads, 1 batch/block.
// Reads the f32 sample (L2-hot from kernel A) — this matches the REFERENCE,
// which paints from the f32 sample. No GEMM on the critical path: store
// stream starts ~1.5 us into the kernel and stays continuous on all CUs.
// Paint expression order is bit-identical to the previous passing kernel.
// ---------------------------------------------------------------------------
__global__ __launch_bounds__(256, 6) void paint_kernel(float* __restrict__ out)
{
    __shared__ unsigned int cnt[CWORDS];          // 16 KB u8-packed canvas
    __shared__ double sp[6][32];                  // SoA spline params * 128
    __shared__ double cfa[NT], cfb[NT], cfc[NT];  // (1-t)^2, 2(1-t)t, t^2

    const int b   = blockIdx.x;
    const int tid = threadIdx.x;

    if (tid < SC6) {
        float sf = out[SAMPLE_OFF + (size_t)b * SC6 + tid];  // L2-hot, 768 B
        sp[tid % 6][tid / 6] = (double)sf * 128.0;           // CANVAS scale
    } else {
        const int t2 = tid - SC6;                 // 0..63
        if (t2 < NT) {
            // np.linspace(0,1,50): t_k = k*fl64(1/49), endpoint forced to 1.0
            double t = (t2 == NT - 1) ? 1.0 : (double)t2 * (1.0 / 49.0);
            double u = 1.0 - t;
            cfa[t2] = u * u;                      // (1-t)**2
            cfb[t2] = (2.0 * u) * t;              // 2*(1-t)*t (ref assoc order)
            cfc[t2] = t * t;                      // t**2
        }
    }
    // zero canvas: all 256 threads, 4 x uint4 each
    {
        uint4* c4 = (uint4*)cnt;                  // 1024 uint4 words
        uint4 z = make_uint4(0u, 0u, 0u, 0u);
        #pragma unroll
        for (int w = tid; w < CWORDS / 4; w += 256) c4[w] = z;
    }
    barrier_lds_only();

    // ---- paint: 32 splines x 50 points, stride 256 ----
    {
        // Thread's spline s = tid&31 is loop-invariant (i += 256 preserves
        // i&31): params hoisted to registers once per block.
        const int s = tid & 31;
        const double P0x = sp[0][s], P0y = sp[1][s];
        const double P1x = sp[2][s], P1y = sp[3][s];
        const double P2x = sp[4][s], P2y = sp[5][s];

        for (int i = tid; i < 32 * NT; i += 256) {
            int kraw = i >> 5;                    // 0..49
            int k    = (kraw * 9) % 50;           // bijection, spreads t per wave
            double a  = cfa[k];
            double bq = cfb[k];
            double c  = cfc[k];
            double px = a * P0x + bq * P1x + c * P2x;  // same op order as prior
            double py = a * P0y + bq * P1y + c * P2y;  // passing rounds
            int cx = (int)rint(px);               // round-half-even == np.round
            int cy = (int)rint(py);

            // clipped y-triple -> u8 increments for 1-2 adjacent 4-px words
            int y0 = min(max(cy - 1, 0), CV - 1);
            int y1 = min(max(cy,     0), CV - 1);
            int y2 = min(max(cy + 1, 0), CV - 1);
            int cb = y0 >> 2;                     // base word-column (0..31)
            unsigned incA = 1u << ((y0 & 3) << 3);
            unsigned incB = 0u;
            unsigned i1 = 1u << ((y1 & 3) << 3);
            unsigned i2 = 1u << ((y2 & 3) << 3);
            if ((y1 >> 2) == cb) incA += i1; else incB += i1;
            if ((y2 >> 2) == cb) incA += i2; else incB += i2;

            int x0 = min(max(cx - 1, 0), CV - 1);
            int x1 = min(max(cx,     0), CV - 1);
            int x2 = min(max(cx + 1, 0), CV - 1);
            int rows[3] = {x0, x1, x2};
            #pragma unroll
            for (int r = 0; r < 3; ++r) {
                int xi = rows[r];
                int base = xi << 5;
                // per-row rotated word layout spreads banks across rows
                atomicAdd(&cnt[base + ((cb + xi) & 31)], incA);
                if (incB) atomicAdd(&cnt[base + ((cb + 1 + xi) & 31)], incB);
            }
        }
    }
    barrier_lds_only();

    // ---- epilogue: clip(0.3 - 0.07*count, 0, 1), float4 stores ----
    vfloat4* ob = (vfloat4*)(out + (size_t)b * CV * CV);
    for (int w = tid; w < CWORDS; w += 256) {
        int xi  = w >> 5;                         // row
        int idx = (xi << 5) + (((w & 31) + xi) & 31);   // undo rotation
        unsigned v = cnt[idx];
        vfloat4 r;
        r.x = fminf(fmaxf(0.3f - 0.07f * (float)( v         & 255u), 0.0f), 1.0f);
        r.y = fminf(fmaxf(0.3f - 0.07f * (float)((v >>  8) & 255u), 0.0f), 1.0f);
        r.z = fminf(fmaxf(0.3f - 0.07f * (float)((v >> 16) & 255u), 0.0f), 1.0f);
        r.w = fminf(fmaxf(0.3f - 0.07f * (float)( v >> 24        ), 0.0f), 1.0f);
        ob[w] = r;                                // coalesced 16 B/lane
    }
}

extern "C" void kernel_launch(void* const* d_in, const int* in_sizes, int n_in,
                              void* d_out, int out_size, void* d_ws, size_t ws_size,
                              hipStream_t stream) {
    const float* x    = (const float*)d_in[0];   // [2048, 256]
    const float* W    = (const float*)d_in[1];   // [256, 192]
    const float* bias = (const float*)d_in[2];   // [192]
    float* out = (float*)d_out;

    gemm_kernel<<<NB / 4, SC6, 0, stream>>>(x, W, bias, out);
    paint_kernel<<<NB, 256, 0, stream>>>(out);
}

// Round 3
// 158.211 us; speedup vs baseline: 1.0378x; 1.0378x over previous
//
#include <hip/hip_runtime.h>
#include <math.h>

// Problem constants (from reference)
#define NB      2048        // batch
#define DIM     256         // input dim
#define SC6     192         // S*6 = 32 splines * 6 params
#define CV      128         // canvas size
#define NT      50          // samples along curve
#define NBPB    4           // batches per block (W amortization)
#define CWORDS  (CV * CV / 4)   // 4096 u8-packed words per canvas
// W_STAMP = -0.07, BG = 0.3, SCALE = 1e-4

// log_prob per batch = 192*( -ln(1e-4) - 0.5*ln(2*pi) )  (raw == mu exactly)
// entropy  per batch = 192*( 0.5 + 0.5*ln(2*pi) + ln(1e-4) )
#define LPV  (1591.9491530441301f)
#define ENV  (-1495.9491530441301f)

// Output layout (flat, return order): sketch | log_prob | entropy | sample
#define SKETCH_N   ((size_t)NB * CV * CV)     // 33,554,432
#define LP_OFF     (SKETCH_N)
#define ENT_OFF    (LP_OFF + NB)
#define SAMPLE_OFF (ENT_OFF + NB)

typedef float vfloat4 __attribute__((ext_vector_type(4)));

// Workgroup barrier waiting ONLY on LDS ops (lgkmcnt), not global stores —
// __syncthreads() would emit s_waitcnt vmcnt(0) and drain epilogue stores on
// the critical path. All cross-phase deps here are LDS-only.
__device__ __forceinline__ void barrier_lds_only() {
    asm volatile("s_waitcnt lgkmcnt(0)\n\ts_barrier" ::: "memory");
}

// Paint one batch's 32 splines into canvas cnv (u8-packed, per-row rotation).
// Thread's spline s = tid&31 is LOOP-INVARIANT: the 6 spline params are
// hoisted to registers. Expression order unchanged -> bit-identical coords
// vs the passing rounds.
__device__ __forceinline__ void do_paint(
    unsigned int* __restrict__ cnv,
    const double (* __restrict__ spb)[32],
    const double* __restrict__ cfa, const double* __restrict__ cfb,
    const double* __restrict__ cfc, int tid)
{
    const int s = tid & 31;
    const double P0x = spb[0][s], P0y = spb[1][s];
    const double P1x = spb[2][s], P1y = spb[3][s];
    const double P2x = spb[4][s], P2y = spb[5][s];

    for (int i = tid; i < 32 * NT; i += 512) {
        int kraw = i >> 5;                    // 0..49
        int k    = (kraw * 9) % 50;           // bijection, spreads t per wave
        double a  = cfa[k];
        double bq = cfb[k];
        double c  = cfc[k];
        double px = a * P0x + bq * P1x + c * P2x;  // same op order as prior
        double py = a * P0y + bq * P1y + c * P2y;  // passing rounds
        int cx = (int)rint(px);               // round-half-even == np.round
        int cy = (int)rint(py);

        // clipped y-triple -> u8 increments for 1-2 adjacent 4-px words
        int y0 = min(max(cy - 1, 0), CV - 1);
        int y1 = min(max(cy,     0), CV - 1);
        int y2 = min(max(cy + 1, 0), CV - 1);
        int cb = y0 >> 2;                     // base word-column (0..31)
        unsigned incA = 1u << ((y0 & 3) << 3);
        unsigned incB = 0u;
        unsigned i1 = 1u << ((y1 & 3) << 3);
        unsigned i2 = 1u << ((y2 & 3) << 3);
        if ((y1 >> 2) == cb) incA += i1; else incB += i1;
        if ((y2 >> 2) == cb) incA += i2; else incB += i2;

        int x0 = min(max(cx - 1, 0), CV - 1);
        int x1 = min(max(cx,     0), CV - 1);
        int x2 = min(max(cx + 1, 0), CV - 1);
        int rows[3] = {x0, x1, x2};
        #pragma unroll
        for (int r = 0; r < 3; ++r) {
            int xi = rows[r];
            int base = xi << 5;
            atomicAdd(&cnv[base + ((cb + xi) & 31)], incA);
            if (incB) atomicAdd(&cnv[base + ((cb + 1 + xi) & 31)], incB);
        }
    }
}

// Emit one batch's canvas. NEW vs round 0:
//   - v==0 fast path: background words (the majority) store a constant,
//     skipping the unpack chain entirely; empty regions are wave-uniform
//     so the branch costs nothing there.
//   - 256-entry LDS LUT of clip(0.3-0.07k,0,1) replaces the per-byte
//     cvt+fma+max+min chain (4 ops -> 1 ds_read; count-0 bytes in mixed
//     words hit the same LUT address -> broadcast, conflict-free).
// Re-zeros the canvas in passing (next paint into it needs zeros).
__device__ __forceinline__ void do_epilogue(
    unsigned int* __restrict__ cnv, float* __restrict__ outb,
    const float* __restrict__ lut, int tid)
{
    vfloat4* ob = (vfloat4*)outb;
    for (int w = tid; w < CWORDS; w += 512) {
        int xi  = w >> 5;                     // row
        int idx = (xi << 5) + (((w & 31) + xi) & 31);
        unsigned v = cnv[idx];
        cnv[idx] = 0u;
        vfloat4 r;
        if (v == 0u) {
            r.x = 0.3f; r.y = 0.3f; r.z = 0.3f; r.w = 0.3f;
        } else {
            r.x = lut[v & 255u];
            r.y = lut[(v >>  8) & 255u];
            r.z = lut[(v >> 16) & 255u];
            r.w = lut[v >> 24];
        }
        ob[w] = r;                            // cached store -> L2
    }
}

// ---------------------------------------------------------------------------
// Fused kernel, one block (512 thr) per FOUR batches; grid 512 = 2 blocks/CU.
//   phase 0: gemm (waves 0-2, f64 bit-exact chains) || zero A+B, coeff+LUT
//   phase k (k=1..3): epilogue(batch k-1) then immediately (no barrier)
//            paint(batch k) into the other canvas; one lgkm-only barrier.
//   tail:    epilogue(batch 3).
// Single launch (round 2 measured ~5.6 us per extra dispatch).
// ---------------------------------------------------------------------------
__global__ __launch_bounds__(512) void fused_kernel(
    const float* __restrict__ x, const float* __restrict__ W,
    const float* __restrict__ bias, float* __restrict__ out)
{
    __shared__ unsigned int cnt[2][CWORDS];       // 2 × 16 KB u8-packed
    __shared__ double sp[NBPB][6][32];            // SoA params*128, 4 batches
    __shared__ double cfa[NT], cfb[NT], cfc[NT];  // (1-t)^2, 2(1-t)t, t^2
    __shared__ float lut[256];                    // clip(0.3-0.07k,0,1)

    const int b0  = blockIdx.x * NBPB;
    const int tid = threadIdx.x;

    if (tid < SC6) {
        // ---- gemm + sigmoid, 4 batches, W loaded once (f64 exact chains) ----
        const int j = tid;
        const float* xb = x + (size_t)b0 * DIM;   // wave-uniform -> s_load
        double a0 = 0.0, a1 = 0.0, a2 = 0.0, a3 = 0.0;
        #pragma unroll 8
        for (int d = 0; d < DIM; ++d) {
            double wd = (double)W[d * SC6 + j];
            a0 = fma((double)xb[d],           wd, a0);
            a1 = fma((double)xb[DIM + d],     wd, a1);
            a2 = fma((double)xb[2 * DIM + d], wd, a2);
            a3 = fma((double)xb[3 * DIM + d], wd, a3);
        }
        double bj = (double)bias[j];
        double s0 = 1.0 / (1.0 + exp(-(a0 + bj)));
        double s1 = 1.0 / (1.0 + exp(-(a1 + bj)));
        double s2 = 1.0 / (1.0 + exp(-(a2 + bj)));
        double s3 = 1.0 / (1.0 + exp(-(a3 + bj)));
        out[SAMPLE_OFF + (size_t)b0 * SC6 + j]       = (float)s0;
        out[SAMPLE_OFF + (size_t)(b0 + 1) * SC6 + j] = (float)s1;
        out[SAMPLE_OFF + (size_t)(b0 + 2) * SC6 + j] = (float)s2;
        out[SAMPLE_OFF + (size_t)(b0 + 3) * SC6 + j] = (float)s3;
        sp[0][j % 6][j / 6] = s0 * 128.0;         // CANVAS scale, SoA
        sp[1][j % 6][j / 6] = s1 * 128.0;
        sp[2][j % 6][j / 6] = s2 * 128.0;
        sp[3][j % 6][j / 6] = s3 * 128.0;
    } else {
        // ---- waves 3-7: zero BOTH canvases + coeff table + LUT + consts ----
        const int t2 = tid - SC6;                 // 0..319
        uint4* c4 = (uint4*)&cnt[0][0];           // 2048 uint4 words
        uint4 z = make_uint4(0u, 0u, 0u, 0u);
        for (int w = t2; w < 2048; w += 320) c4[w] = z;
        if (t2 < NT) {
            // np.linspace(0,1,50): t_k = k*fl64(1/49), endpoint forced to 1.0
            double t = (t2 == NT - 1) ? 1.0 : (double)t2 * (1.0 / 49.0);
            double u = 1.0 - t;
            cfa[t2] = u * u;                      // (1-t)**2
            cfb[t2] = (2.0 * u) * t;              // 2*(1-t)*t (ref assoc order)
            cfc[t2] = t * t;                      // t**2
        }
        if (t2 < 256) {                           // same arithmetic as before:
            lut[t2] = fminf(fmaxf(0.3f - 0.07f * (float)t2, 0.0f), 1.0f);
        }
        if (t2 >= 256 && t2 < 260) out[LP_OFF  + b0 + (t2 - 256)] = LPV;
        if (t2 >= 260 && t2 < 264) out[ENT_OFF + b0 + (t2 - 260)] = ENV;
    }
    barrier_lds_only();

    // ---- pipelined paint/epilogue over 4 batches, 2 canvases ----
    #pragma unroll
    for (int bb = 0; bb < NBPB; ++bb) {
        if (bb > 0) {
            // epilogue of previous batch first: stores go in flight, then
            // this wave rolls straight into paint (disjoint canvases).
            do_epilogue(cnt[(bb - 1) & 1],
                        out + (size_t)(b0 + bb - 1) * CV * CV, lut, tid);
        }
        do_paint(cnt[bb & 1], sp[bb], cfa, cfb, cfc, tid);
        barrier_lds_only();
    }
    do_epilogue(cnt[(NBPB - 1) & 1],
                out + (size_t)(b0 + NBPB - 1) * CV * CV, lut, tid);
}

extern "C" void kernel_launch(void* const* d_in, const int* in_sizes, int n_in,
                              void* d_out, int out_size, void* d_ws, size_t ws_size,
                              hipStream_t stream) {
    const float* x    = (const float*)d_in[0];   // [2048, 256]
    const float* W    = (const float*)d_in[1];   // [256, 192]
    const float* bias = (const float*)d_in[2];   // [192]
    float* out = (float*)d_out;

    fused_kernel<<<NB / NBPB, 512, 0, stream>>>(x, W, bias, out);
}